// Round 6
// baseline (157.873 us; speedup 1.0000x reference)
//
#include <hip/hip_runtime.h>
#include <cstdint>
#include <cstddef>

using u16    = uint16_t;
using u16x4  = __attribute__((ext_vector_type(4))) uint16_t;
using u16x8  = __attribute__((ext_vector_type(8))) uint16_t;
using bf16x2 = __attribute__((ext_vector_type(2))) __bf16;
using bf16x8 = __attribute__((ext_vector_type(8))) __bf16;
using f32x4  = __attribute__((ext_vector_type(4))) float;
using f32x16 = __attribute__((ext_vector_type(16))) float;

// B=2, N=2048, C=768, H=12, D=64 ; M = B*N = 4096
// Inputs fp32; intermediates bf16; OUTPUT fp32.
__device__ __forceinline__ u16 f2b(float f) {
    union { float f; uint32_t u; } x; x.f = f;
    uint32_t r = x.u + 0x7FFFu + ((x.u >> 16) & 1u);
    return (u16)(r >> 16);
}
// hardware bf16 pack (RNE; fuses to v_cvt_pk_bf16_f32 on gfx950)
__device__ __forceinline__ uint32_t pk2(float a, float b) {
    bf16x2 t; t[0] = (__bf16)a; t[1] = (__bf16)b;
    return __builtin_bit_cast(uint32_t, t);
}
// 16B fragment from two 8B LDS reads
__device__ __forceinline__ bf16x8 ld8(const u16* p) {
    union { u16x8 v; u16x4 h[2]; } r;
    r.h[0] = *(const u16x4*)p;
    r.h[1] = *(const u16x4*)(p + 4);
    return __builtin_bit_cast(bf16x8, r.v);
}
__device__ __forceinline__ u16x8 ld8u(const u16* p) {
    union { u16x8 v; u16x4 h[2]; } r;
    r.h[0] = *(const u16x4*)p;
    r.h[1] = *(const u16x4*)(p + 4);
    return r.v;
}
// hardware exp2 (v_exp_f32)
__device__ __forceinline__ float ex2(float x) {
#if __has_builtin(__builtin_amdgcn_exp2f)
    return __builtin_amdgcn_exp2f(x);
#else
    return __expf(x * 0.6931471805599453f);
#endif
}

// async global->LDS, 16B per lane, LDS dest = wave-uniform base + lane*16
__device__ __forceinline__ void load16_async(const u16* g, u16* lds_base) {
    __builtin_amdgcn_global_load_lds(
        (const __attribute__((address_space(1))) u16*)g,
        (__attribute__((address_space(3))) u16*)(uint32_t)(uintptr_t)lds_base,
        16, 0, 0);
}

// fp32 -> bf16 bulk converter for x, w_qkv, w_proj (counts in float4 units)
__global__ void conv_k(const float* __restrict__ x,  u16* __restrict__ xb,  int nx4,
                       const float* __restrict__ w1, u16* __restrict__ w1b, int n14,
                       const float* __restrict__ w2, u16* __restrict__ w2b, int n24)
{
    const int t   = blockIdx.x * blockDim.x + threadIdx.x;
    const int stp = gridDim.x * blockDim.x;
    for (int i = t; i < nx4; i += stp) {
        f32x4 v = ((const f32x4*)x)[i];
        u16x4 o;
        #pragma unroll
        for (int e = 0; e < 4; e++) o[e] = f2b(v[e]);
        ((u16x4*)xb)[i] = o;
    }
    for (int i = t; i < n14; i += stp) {
        f32x4 v = ((const f32x4*)w1)[i];
        u16x4 o;
        #pragma unroll
        for (int e = 0; e < 4; e++) o[e] = f2b(v[e]);
        ((u16x4*)w1b)[i] = o;
    }
    for (int i = t; i < n24; i += stp) {
        f32x4 v = ((const f32x4*)w2)[i];
        u16x4 o;
        #pragma unroll
        for (int e = 0; e < 4; e++) o[e] = f2b(v[e]);
        ((u16x4*)w2b)[i] = o;
    }
}

// QKV: C = A[4096,768] @ W[2304,768]^T + bias ; 128x128 tiles, BK=64 + XOR swizzle.
// Q blocks (col0<768): direct row-major store to Qw.
// K blocks (768<=col0<1536): T2[token][feat] transpose -> fragment-major
//   Kt[bh][kg][c][hl][lr][8]: element = K[kg*32+lr][c*16+hl*8+e] (k local to head).
// V blocks (col0>=1536): T[feat][token] transpose -> fragment-major
//   Vt[bh][kg][f][hl*32+lr][8]: element = V[key kg*32 + (f&1)*16 + hl*4 +
//   (e&3)+8*(e>>2)][d=(f>>1)*32+lr]  (sigma-ordered for in-register-P PV).
__global__ __launch_bounds__(256, 3) void gemm_qkv(
    const u16* __restrict__ A, const u16* __restrict__ W,
    const float* __restrict__ bias,
    u16* __restrict__ O0, u16* __restrict__ Kt, u16* __restrict__ Vt)
{
    // K-loop: As [128][64] | Bs [128][64] (32 KB). Epilogue overlays: T/T2 [128][132] u16
    __shared__ alignas(16) char smem[33792];
    u16* As = (u16*)smem;
    u16* Bs = (u16*)(smem + 16384);
    u16* T  = (u16*)smem;

    const int tid  = threadIdx.x;
    const int wid  = tid >> 6, lane = tid & 63;
    const int quad = lane >> 4, lc = lane & 15;
    const int row0 = blockIdx.x * 128, col0 = blockIdx.y * 128;
    const int wm   = (wid >> 1) * 64, wn = (wid & 1) * 64;

    const int srA = wid * 8 + (lane >> 3);
    const int scA = ((lane & 7) ^ ((lane >> 3) & 7)) * 8;
    const int rc0 = ((0*4 + quad) ^ (lc & 7)) * 8;
    const int rc1 = ((1*4 + quad) ^ (lc & 7)) * 8;

    f32x4 acc[4][4] = {};

    for (int k0 = 0; k0 < 768; k0 += 64) {
        __syncthreads();
        #pragma unroll
        for (int c = 0; c < 4; c++) {
            load16_async(&A[(row0 + c*32 + srA) * 768 + k0 + scA], &As[(c*32 + wid*8) * 64]);
            load16_async(&W[(col0 + c*32 + srA) * 768 + k0 + scA], &Bs[(c*32 + wid*8) * 64]);
        }
        __syncthreads();

        #pragma unroll
        for (int s = 0; s < 2; s++) {
            const int rc = s ? rc1 : rc0;
            bf16x8 a[4], b[4];
            #pragma unroll
            for (int i = 0; i < 4; i++)
                a[i] = __builtin_bit_cast(bf16x8, *(const u16x8*)&As[(wm + i*16 + lc)*64 + rc]);
            #pragma unroll
            for (int j = 0; j < 4; j++)
                b[j] = __builtin_bit_cast(bf16x8, *(const u16x8*)&Bs[(wn + j*16 + lc)*64 + rc]);
            #pragma unroll
            for (int i = 0; i < 4; i++)
                #pragma unroll
                for (int j = 0; j < 4; j++)
                    acc[i][j] = __builtin_amdgcn_mfma_f32_16x16x32_bf16(a[i], b[j], acc[i][j], 0, 0, 0);
        }
    }

    if (col0 < 768) {
        // Q blocks: direct row-major store
        #pragma unroll
        for (int i = 0; i < 4; i++) {
            #pragma unroll
            for (int j = 0; j < 4; j++) {
                const int gc = col0 + wn + j*16 + lc;
                const float bv = bias[gc];
                #pragma unroll
                for (int r = 0; r < 4; r++) {
                    const int gr = row0 + wm + i*16 + quad*4 + r;
                    O0[gr * 768 + gc] = f2b(acc[i][j][r] + bv);
                }
            }
        }
    } else if (col0 < 1536) {
        // K block: transpose to T2[token][feature] (stride 132), then
        // fragment-major gather to Kt.
        __syncthreads();   // all K-loop LDS reads done before overlay write
        u16* T2 = T;
        #pragma unroll
        for (int j = 0; j < 4; j++) {
            const int fl = wn + j*16 + lc;               // local feature
            const float bv = bias[col0 + fl];
            #pragma unroll
            for (int i = 0; i < 4; i++)
                #pragma unroll
                for (int r = 0; r < 4; r++)
                    T2[(wm + i*16 + quad*4 + r)*132 + fl] = f2b(acc[i][j][r] + bv);
        }
        __syncthreads();

        const int t7 = tid & 127, hloc = tid >> 7;
        const int bh = (row0 >> 11) * 12 + ((col0 - 768) >> 6) + hloc;
        const int kg0 = (row0 & 2047) >> 5;
        u16* dst = Kt + (size_t)bh * 131072 + (size_t)kg0 * 2048;
        #pragma unroll
        for (int i = 0; i < 8; i++) {
            const int idx = t7 + 128*i;                  // 0..1023 per head
            const int lr = idx & 31, hl = (idx >> 5) & 1;
            const int c  = (idx >> 6) & 3, lkg = idx >> 8;
            const u16* src = &T2[(lkg*32 + lr)*132 + hloc*64 + c*16 + hl*8];
            *(u16x8*)&dst[lkg*2048 + c*512 + hl*256 + lr*8] = ld8u(src);
        }
    } else {
        // V block: transpose to T[feature][token] (stride 132), then
        // fragment-major (sigma-ordered) gather to Vt.
        __syncthreads();   // all K-loop LDS reads done before overlay write
        #pragma unroll
        for (int j = 0; j < 4; j++) {
            const int cl = wn + j*16 + lc;               // local feature (d)
            const float bv = bias[col0 + cl];
            #pragma unroll
            for (int i = 0; i < 4; i++) {
                uint2 w;
                w.x = pk2(acc[i][j][0] + bv, acc[i][j][1] + bv);
                w.y = pk2(acc[i][j][2] + bv, acc[i][j][3] + bv);
                *(uint2*)&T[cl*132 + wm + i*16 + quad*4] = w;   // 4 consecutive tokens
            }
        }
        __syncthreads();

        const int t7 = tid & 127, hloc = tid >> 7;
        const int bh = (row0 >> 11) * 12 + ((col0 - 1536) >> 6) + hloc;
        const int kg0 = (row0 & 2047) >> 5;
        u16* dst = Vt + (size_t)bh * 131072 + (size_t)kg0 * 2048;
        #pragma unroll
        for (int i = 0; i < 8; i++) {
            const int idx = t7 + 128*i;                  // 0..1023 per head
            const int L = idx & 63, f = (idx >> 6) & 3, lkg = idx >> 8;
            const int lr = L & 31, hl = L >> 5;
            const u16* src = &T[(hloc*64 + (f>>1)*32 + lr)*132 + lkg*32 + (f&1)*16 + hl*4];
            union { u16x8 v; u16x4 h[2]; } rr;
            rr.h[0] = *(const u16x4*)src;        // keys +0..3
            rr.h[1] = *(const u16x4*)(src + 8);  // keys +8..11
            *(u16x8*)&dst[lkg*2048 + f*512 + L*8] = rr.v;
        }
    }
}

// Proj: 64x64 tiles (768 blocks). BK=64 + XOR swizzle. fp32 out + bias.
__global__ __launch_bounds__(256, 4) void gemm_proj(
    const u16* __restrict__ A, const u16* __restrict__ W,
    const float* __restrict__ bias, float* __restrict__ F0)
{
    __shared__ alignas(16) u16 As[64 * 64];
    __shared__ alignas(16) u16 Bs[64 * 64];
    const int tid  = threadIdx.x;
    const int wid  = tid >> 6, lane = tid & 63;
    const int quad = lane >> 4, lc = lane & 15;
    const int row0 = blockIdx.x * 64, col0 = blockIdx.y * 64;
    const int wm   = (wid >> 1) * 32, wn = (wid & 1) * 32;

    const int srA = wid * 8 + (lane >> 3);
    const int scA = ((lane & 7) ^ ((lane >> 3) & 7)) * 8;
    const int rc0 = ((0*4 + quad) ^ (lc & 7)) * 8;
    const int rc1 = ((1*4 + quad) ^ (lc & 7)) * 8;

    f32x4 acc[2][2] = {};

    for (int k0 = 0; k0 < 768; k0 += 64) {
        __syncthreads();
        #pragma unroll
        for (int c = 0; c < 2; c++) {
            load16_async(&A[(row0 + c*32 + srA) * 768 + k0 + scA], &As[(c*32 + wid*8) * 64]);
            load16_async(&W[(col0 + c*32 + srA) * 768 + k0 + scA], &Bs[(c*32 + wid*8) * 64]);
        }
        __syncthreads();

        #pragma unroll
        for (int s = 0; s < 2; s++) {
            const int rc = s ? rc1 : rc0;
            bf16x8 a[2], b[2];
            #pragma unroll
            for (int i = 0; i < 2; i++)
                a[i] = __builtin_bit_cast(bf16x8, *(const u16x8*)&As[(wm + i*16 + lc)*64 + rc]);
            #pragma unroll
            for (int j = 0; j < 2; j++)
                b[j] = __builtin_bit_cast(bf16x8, *(const u16x8*)&Bs[(wn + j*16 + lc)*64 + rc]);
            #pragma unroll
            for (int i = 0; i < 2; i++)
                #pragma unroll
                for (int j = 0; j < 2; j++)
                    acc[i][j] = __builtin_amdgcn_mfma_f32_16x16x32_bf16(a[i], b[j], acc[i][j], 0, 0, 0);
        }
    }

    #pragma unroll
    for (int i = 0; i < 2; i++)
        #pragma unroll
        for (int j = 0; j < 2; j++) {
            const int gc = col0 + wn + j*16 + lc;
            const float bv = bias[gc];
            #pragma unroll
            for (int r = 0; r < 4; r++) {
                const int gr = row0 + wm + i*16 + quad*4 + r;
                F0[gr * 768 + gc] = acc[i][j][r] + bv;
            }
        }
}

// Flash attention, R5: zero-LDS, zero-barrier main loop over FRAGMENT-MAJOR
// K/V (coalesced: every fragment load = base + lane*16B = one 1KB wave txn).
// 768 blocks (bh x 32 q-tiles of 64), 4 independent waves: wave w handles
// key-groups {4i + w}. Per wave-iter (32 keys x 64 q): 16 MFMA 32x32x16,
// in-register P (no Ps), 32 ex2. Epilogue = R3's verified Obuf reduction.
__global__ __launch_bounds__(256, 3) void attn_k(
    const u16* __restrict__ Q, const u16* __restrict__ Kt,
    const u16* __restrict__ Vt, u16* __restrict__ O)
{
    __shared__ alignas(16) char lds[34304];
    float* Obuf = (float*)lds;             // [4][64][33] f32 = 33792 B
    float* Lbuf = (float*)(lds + 33792);   // [4][32] f32

    const int tid  = threadIdx.x;
    const int wid  = tid >> 6, lane = tid & 63;
    const int hl   = lane >> 5;            // k-slot half selector
    const int lr   = lane & 31;
    const int li = blockIdx.x;
    const int bh = li >> 5, qt = li & 31;
    const int b = bh / 12, h = bh - b * 12;
    const int q0 = qt * 64;

    const u16* Qp = Q + ((size_t)b * 2048) * 768 + h * 64;
    u16*       Op = O + ((size_t)b * 2048) * 768 + h * 64;
    const u16* Kb = Kt + (size_t)bh * 131072;
    const u16* Vb = Vt + (size_t)bh * 131072;
    const int lo8 = lane * 8;

    // Q fragments (B-operand), two q-halves; scale = 1/8 * log2(e)
    const float qs = 0.125f * 1.4426950408889634f;
    bf16x8 qf[2][4];
    #pragma unroll
    for (int qh = 0; qh < 2; qh++)
        #pragma unroll
        for (int c = 0; c < 4; c++) {
            u16x8 t = *(const u16x8*)&Qp[(q0 + qh*32 + lr) * 768 + c*16 + hl*8];
            bf16x8 sc;
            #pragma unroll
            for (int e = 0; e < 8; e++) {
                union { uint32_t u; float f; } z; z.u = ((uint32_t)t[e]) << 16;
                sc[e] = (__bf16)(z.f * qs);
            }
            qf[qh][c] = sc;
        }

    float l0 = 0.f, l1 = 0.f;
    f32x16 o00 = {}, o01 = {}, o10 = {}, o11 = {};  // [qh][d-half], q = lr

    // prefetch K fragments for key-group wid (iter 0)
    bf16x8 kreg[4];
    #pragma unroll
    for (int c = 0; c < 4; c++)
        kreg[c] = __builtin_bit_cast(bf16x8, *(const u16x8*)&Kb[wid*2048 + c*512 + lo8]);

    for (int kt = 0; kt < 16; kt++) {
        const int kg = kt*4 + wid;
        const u16* vt = &Vb[(size_t)kg * 2048 + lo8];
        // V fragment loads issued early; consumed after QK^T+softmax
        u16x8 va0r = *(const u16x8*)&vt[0];
        u16x8 va1r = *(const u16x8*)&vt[512];
        u16x8 vb0r = *(const u16x8*)&vt[1024];
        u16x8 vb1r = *(const u16x8*)&vt[1536];

        // S^T both q-halves: own 32 keys x 64 q, K=64 in 4 chunks
        f32x16 s0 = {}, s1 = {};
        __builtin_amdgcn_s_setprio(1);
        #pragma unroll
        for (int c = 0; c < 4; c++)
            s0 = __builtin_amdgcn_mfma_f32_32x32x16_bf16(kreg[c], qf[0][c], s0, 0, 0, 0);
        #pragma unroll
        for (int c = 0; c < 4; c++)
            s1 = __builtin_amdgcn_mfma_f32_32x32x16_bf16(kreg[c], qf[1][c], s1, 0, 0, 0);
        __builtin_amdgcn_s_setprio(0);

        // prefetch K for next tile (kreg free after QK^T)
        if (kt < 15) {
            #pragma unroll
            for (int c = 0; c < 4; c++)
                kreg[c] = __builtin_bit_cast(bf16x8, *(const u16x8*)&Kb[(size_t)(kg + 4)*2048 + c*512 + lo8]);
        }

        // ---- q-half 0: softmax numerator (base-2) + in-reg P repack + PV ----
        #pragma unroll
        for (int r = 0; r < 16; r++) {
            float p = ex2(s0[r]);
            s0[r] = p;
            l0 += p;
        }
        union { bf16x8 v; uint32_t w[4]; } p00, p01;
        #pragma unroll
        for (int e2 = 0; e2 < 4; e2++) {
            p00.w[e2] = pk2(s0[2*e2],     s0[2*e2 + 1]);
            p01.w[e2] = pk2(s0[8 + 2*e2], s0[8 + 2*e2 + 1]);
        }
        {
            bf16x8 va0 = __builtin_bit_cast(bf16x8, va0r);
            bf16x8 va1 = __builtin_bit_cast(bf16x8, va1r);
            bf16x8 vb0 = __builtin_bit_cast(bf16x8, vb0r);
            bf16x8 vb1 = __builtin_bit_cast(bf16x8, vb1r);
            __builtin_amdgcn_s_setprio(1);
            o00 = __builtin_amdgcn_mfma_f32_32x32x16_bf16(va0, p00.v, o00, 0, 0, 0);
            o00 = __builtin_amdgcn_mfma_f32_32x32x16_bf16(va1, p01.v, o00, 0, 0, 0);
            o01 = __builtin_amdgcn_mfma_f32_32x32x16_bf16(vb0, p00.v, o01, 0, 0, 0);
            o01 = __builtin_amdgcn_mfma_f32_32x32x16_bf16(vb1, p01.v, o01, 0, 0, 0);
            __builtin_amdgcn_s_setprio(0);
        }

        // ---- q-half 1 ----
        #pragma unroll
        for (int r = 0; r < 16; r++) {
            float p = ex2(s1[r]);
            s1[r] = p;
            l1 += p;
        }
        union { bf16x8 v; uint32_t w[4]; } p10, p11;
        #pragma unroll
        for (int e2 = 0; e2 < 4; e2++) {
            p10.w[e2] = pk2(s1[2*e2],     s1[2*e2 + 1]);
            p11.w[e2] = pk2(s1[8 + 2*e2], s1[8 + 2*e2 + 1]);
        }
        {
            bf16x8 va0 = __builtin_bit_cast(bf16x8, va0r);
            bf16x8 va1 = __builtin_bit_cast(bf16x8, va1r);
            bf16x8 vb0 = __builtin_bit_cast(bf16x8, vb0r);
            bf16x8 vb1 = __builtin_bit_cast(bf16x8, vb1r);
            __builtin_amdgcn_s_setprio(1);
            o10 = __builtin_amdgcn_mfma_f32_32x32x16_bf16(va0, p10.v, o10, 0, 0, 0);
            o10 = __builtin_amdgcn_mfma_f32_32x32x16_bf16(va1, p11.v, o10, 0, 0, 0);
            o11 = __builtin_amdgcn_mfma_f32_32x32x16_bf16(vb0, p10.v, o11, 0, 0, 0);
            o11 = __builtin_amdgcn_mfma_f32_32x32x16_bf16(vb1, p11.v, o11, 0, 0, 0);
            __builtin_amdgcn_s_setprio(0);
        }
    }

    // ---- epilogue: cross-wave reduction over key slices, per q-half ----
    l0 += __shfl_xor(l0, 32);    // combine hl halves (same q, disjoint keys)
    l1 += __shfl_xor(l1, 32);

    const int q  = tid & 31;     // epilogue q (within half)
    const int dblk = tid >> 5;   // epilogue d block (0..7), 8 d each

    // q-half 0
    if (lane < 32) Lbuf[wid*32 + lr] = l0;
    #pragma unroll
    for (int r = 0; r < 16; r++) {
        const int dr = (r & 3) + 8*(r >> 2) + 4*hl;
        Obuf[(wid*64 + dr)*33 + lr]      = o00[r];
        Obuf[(wid*64 + 32 + dr)*33 + lr] = o01[r];
    }
    __syncthreads();
    {
        const float linv = 1.0f / (Lbuf[q] + Lbuf[32 + q] + Lbuf[64 + q] + Lbuf[96 + q]);
        u16x8 ov;
        #pragma unroll
        for (int j = 0; j < 8; j++) {
            const int d = dblk*8 + j;
            const float sum = Obuf[(0*64 + d)*33 + q] + Obuf[(1*64 + d)*33 + q] +
                              Obuf[(2*64 + d)*33 + q] + Obuf[(3*64 + d)*33 + q];
            ov[j] = f2b(sum * linv);
        }
        *(u16x8*)&Op[(size_t)(q0 + q) * 768 + dblk*8] = ov;
    }
    __syncthreads();

    // q-half 1
    if (lane < 32) Lbuf[wid*32 + lr] = l1;
    #pragma unroll
    for (int r = 0; r < 16; r++) {
        const int dr = (r & 3) + 8*(r >> 2) + 4*hl;
        Obuf[(wid*64 + dr)*33 + lr]      = o10[r];
        Obuf[(wid*64 + 32 + dr)*33 + lr] = o11[r];
    }
    __syncthreads();
    {
        const float linv = 1.0f / (Lbuf[q] + Lbuf[32 + q] + Lbuf[64 + q] + Lbuf[96 + q]);
        u16x8 ov;
        #pragma unroll
        for (int j = 0; j < 8; j++) {
            const int d = dblk*8 + j;
            const float sum = Obuf[(0*64 + d)*33 + q] + Obuf[(1*64 + d)*33 + q] +
                              Obuf[(2*64 + d)*33 + q] + Obuf[(3*64 + d)*33 + q];
            ov[j] = f2b(sum * linv);
        }
        *(u16x8*)&Op[(size_t)(q0 + 32 + q) * 768 + dblk*8] = ov;
    }
}

extern "C" void kernel_launch(void* const* d_in, const int* in_sizes, int n_in,
                              void* d_out, int out_size, void* d_ws, size_t ws_size,
                              hipStream_t stream)
{
    const float* x    = (const float*)d_in[0];   // [2,2048,768] fp32
    const float* wqkv = (const float*)d_in[1];   // [2304,768]   fp32
    const float* bqkv = (const float*)d_in[2];   // [2304]       fp32
    const float* wp   = (const float*)d_in[3];   // [768,768]    fp32
    const float* bp   = (const float*)d_in[4];   // [768]        fp32
    float* out = (float*)d_out;                  // [2,2048,768] fp32
    char* ws = (char*)d_ws;

    // ws: Qw 6.29M | Vt 6.29M | wqkvb 3.54M | wpb 1.18M = 17.3M (proven available)
    // d_out (12.58M fp32): front = Kt (fragment-major bf16, 6.29M), back = xb
    // bf16 6.29M; both dead before gemm_proj overwrites d_out (stream-ordered).
    u16* Qw    = (u16*)(ws);
    u16* Vt    = (u16*)(ws + 6291456);
    u16* wqkvb = (u16*)(ws + 12582912);
    u16* wpb   = (u16*)(ws + 16121856);
    u16* Kt    = (u16*)d_out;
    u16* xb    = (u16*)((char*)d_out + 6291456);

    conv_k<<<512, 256, 0, stream>>>(x, xb, 3145728/4, wqkv, wqkvb, 1769472/4, wp, wpb, 589824/4);
    gemm_qkv<<<dim3(32, 18), 256, 0, stream>>>(xb, wqkvb, bqkv, Qw, Kt, Vt);
    attn_k<<<768, 256, 0, stream>>>(Qw, Kt, Vt, Qw);
    gemm_proj<<<dim3(64, 12), 256, 0, stream>>>(Qw, wpb, bp, out);
}

// Round 7
// 135.454 us; speedup vs baseline: 1.1655x; 1.1655x over previous
//
#include <hip/hip_runtime.h>
#include <cstdint>
#include <cstddef>

using u16    = uint16_t;
using u16x4  = __attribute__((ext_vector_type(4))) uint16_t;
using u16x8  = __attribute__((ext_vector_type(8))) uint16_t;
using bf16x2 = __attribute__((ext_vector_type(2))) __bf16;
using bf16x8 = __attribute__((ext_vector_type(8))) __bf16;
using f32x4  = __attribute__((ext_vector_type(4))) float;
using f32x16 = __attribute__((ext_vector_type(16))) float;

// B=2, N=2048, C=768, H=12, D=64 ; M = B*N = 4096
// Inputs fp32; intermediates bf16; OUTPUT fp32.
__device__ __forceinline__ u16 f2b(float f) {
    union { float f; uint32_t u; } x; x.f = f;
    uint32_t r = x.u + 0x7FFFu + ((x.u >> 16) & 1u);
    return (u16)(r >> 16);
}
// hardware bf16 pack (RNE; fuses to v_cvt_pk_bf16_f32 on gfx950)
__device__ __forceinline__ uint32_t pk2(float a, float b) {
    bf16x2 t; t[0] = (__bf16)a; t[1] = (__bf16)b;
    return __builtin_bit_cast(uint32_t, t);
}
__device__ __forceinline__ u16x8 ld8u(const u16* p) {
    union { u16x8 v; u16x4 h[2]; } r;
    r.h[0] = *(const u16x4*)p;
    r.h[1] = *(const u16x4*)(p + 4);
    return r.v;
}
// hardware exp2 (v_exp_f32)
__device__ __forceinline__ float ex2(float x) {
#if __has_builtin(__builtin_amdgcn_exp2f)
    return __builtin_amdgcn_exp2f(x);
#else
    return __expf(x * 0.6931471805599453f);
#endif
}

// async global->LDS, 16B per lane, LDS dest = wave-uniform base + lane*16
__device__ __forceinline__ void load16_async(const u16* g, u16* lds_base) {
    __builtin_amdgcn_global_load_lds(
        (const __attribute__((address_space(1))) u16*)g,
        (__attribute__((address_space(3))) u16*)(uint32_t)(uintptr_t)lds_base,
        16, 0, 0);
}

// fp32 -> bf16 bulk converter for x, w_qkv, w_proj (counts in float4 units)
__global__ void conv_k(const float* __restrict__ x,  u16* __restrict__ xb,  int nx4,
                       const float* __restrict__ w1, u16* __restrict__ w1b, int n14,
                       const float* __restrict__ w2, u16* __restrict__ w2b, int n24)
{
    const int t   = blockIdx.x * blockDim.x + threadIdx.x;
    const int stp = gridDim.x * blockDim.x;
    for (int i = t; i < nx4; i += stp) {
        f32x4 v = ((const f32x4*)x)[i];
        u16x4 o;
        #pragma unroll
        for (int e = 0; e < 4; e++) o[e] = f2b(v[e]);
        ((u16x4*)xb)[i] = o;
    }
    for (int i = t; i < n14; i += stp) {
        f32x4 v = ((const f32x4*)w1)[i];
        u16x4 o;
        #pragma unroll
        for (int e = 0; e < 4; e++) o[e] = f2b(v[e]);
        ((u16x4*)w1b)[i] = o;
    }
    for (int i = t; i < n24; i += stp) {
        f32x4 v = ((const f32x4*)w2)[i];
        u16x4 o;
        #pragma unroll
        for (int e = 0; e < 4; e++) o[e] = f2b(v[e]);
        ((u16x4*)w2b)[i] = o;
    }
}

// QKV: C = A[4096,768] @ W[2304,768]^T + bias ; 128x128 tiles, BK=64 + XOR swizzle.
// Q blocks (col0<768): direct row-major store to Qw.
// K blocks (768<=col0<1536): T2[token][feat] transpose -> fragment-major
//   Kt[bh][kg][c][hl][lr][8]: element = K[kg*32+lr][c*16+hl*8+e] (k local to head).
// V blocks (col0>=1536): T[feat][token] transpose -> fragment-major
//   Vt[bh][kg][f][hl*32+lr][8]: element = V[key kg*32 + (f&1)*16 + hl*4 +
//   (e&3)+8*(e>>2)][d=(f>>1)*32+lr]  (sigma-ordered for in-register-P PV).
__global__ __launch_bounds__(256, 3) void gemm_qkv(
    const u16* __restrict__ A, const u16* __restrict__ W,
    const float* __restrict__ bias,
    u16* __restrict__ O0, u16* __restrict__ Kt, u16* __restrict__ Vt)
{
    // K-loop: As [128][64] | Bs [128][64] (32 KB). Epilogue overlays: T/T2 [128][132] u16
    __shared__ alignas(16) char smem[33792];
    u16* As = (u16*)smem;
    u16* Bs = (u16*)(smem + 16384);
    u16* T  = (u16*)smem;

    const int tid  = threadIdx.x;
    const int wid  = tid >> 6, lane = tid & 63;
    const int quad = lane >> 4, lc = lane & 15;
    const int row0 = blockIdx.x * 128, col0 = blockIdx.y * 128;
    const int wm   = (wid >> 1) * 64, wn = (wid & 1) * 64;

    const int srA = wid * 8 + (lane >> 3);
    const int scA = ((lane & 7) ^ ((lane >> 3) & 7)) * 8;
    const int rc0 = ((0*4 + quad) ^ (lc & 7)) * 8;
    const int rc1 = ((1*4 + quad) ^ (lc & 7)) * 8;

    f32x4 acc[4][4] = {};

    for (int k0 = 0; k0 < 768; k0 += 64) {
        __syncthreads();
        #pragma unroll
        for (int c = 0; c < 4; c++) {
            load16_async(&A[(row0 + c*32 + srA) * 768 + k0 + scA], &As[(c*32 + wid*8) * 64]);
            load16_async(&W[(col0 + c*32 + srA) * 768 + k0 + scA], &Bs[(c*32 + wid*8) * 64]);
        }
        __syncthreads();

        #pragma unroll
        for (int s = 0; s < 2; s++) {
            const int rc = s ? rc1 : rc0;
            bf16x8 a[4], b[4];
            #pragma unroll
            for (int i = 0; i < 4; i++)
                a[i] = __builtin_bit_cast(bf16x8, *(const u16x8*)&As[(wm + i*16 + lc)*64 + rc]);
            #pragma unroll
            for (int j = 0; j < 4; j++)
                b[j] = __builtin_bit_cast(bf16x8, *(const u16x8*)&Bs[(wn + j*16 + lc)*64 + rc]);
            #pragma unroll
            for (int i = 0; i < 4; i++)
                #pragma unroll
                for (int j = 0; j < 4; j++)
                    acc[i][j] = __builtin_amdgcn_mfma_f32_16x16x32_bf16(a[i], b[j], acc[i][j], 0, 0, 0);
        }
    }

    if (col0 < 768) {
        // Q blocks: direct row-major store
        #pragma unroll
        for (int i = 0; i < 4; i++) {
            #pragma unroll
            for (int j = 0; j < 4; j++) {
                const int gc = col0 + wn + j*16 + lc;
                const float bv = bias[gc];
                #pragma unroll
                for (int r = 0; r < 4; r++) {
                    const int gr = row0 + wm + i*16 + quad*4 + r;
                    O0[gr * 768 + gc] = f2b(acc[i][j][r] + bv);
                }
            }
        }
    } else if (col0 < 1536) {
        // K block: transpose to T2[token][feature] (stride 132), then
        // fragment-major gather to Kt.
        __syncthreads();   // all K-loop LDS reads done before overlay write
        u16* T2 = T;
        #pragma unroll
        for (int j = 0; j < 4; j++) {
            const int fl = wn + j*16 + lc;               // local feature
            const float bv = bias[col0 + fl];
            #pragma unroll
            for (int i = 0; i < 4; i++)
                #pragma unroll
                for (int r = 0; r < 4; r++)
                    T2[(wm + i*16 + quad*4 + r)*132 + fl] = f2b(acc[i][j][r] + bv);
        }
        __syncthreads();

        const int t7 = tid & 127, hloc = tid >> 7;
        const int bh = (row0 >> 11) * 12 + ((col0 - 768) >> 6) + hloc;
        const int kg0 = (row0 & 2047) >> 5;
        u16* dst = Kt + (size_t)bh * 131072 + (size_t)kg0 * 2048;
        #pragma unroll
        for (int i = 0; i < 8; i++) {
            const int idx = t7 + 128*i;                  // 0..1023 per head
            const int lr = idx & 31, hl = (idx >> 5) & 1;
            const int c  = (idx >> 6) & 3, lkg = idx >> 8;
            const u16* src = &T2[(lkg*32 + lr)*132 + hloc*64 + c*16 + hl*8];
            *(u16x8*)&dst[lkg*2048 + c*512 + hl*256 + lr*8] = ld8u(src);
        }
    } else {
        // V block: transpose to T[feature][token] (stride 132), then
        // fragment-major (sigma-ordered) gather to Vt.
        __syncthreads();   // all K-loop LDS reads done before overlay write
        #pragma unroll
        for (int j = 0; j < 4; j++) {
            const int cl = wn + j*16 + lc;               // local feature (d)
            const float bv = bias[col0 + cl];
            #pragma unroll
            for (int i = 0; i < 4; i++) {
                uint2 w;
                w.x = pk2(acc[i][j][0] + bv, acc[i][j][1] + bv);
                w.y = pk2(acc[i][j][2] + bv, acc[i][j][3] + bv);
                *(uint2*)&T[cl*132 + wm + i*16 + quad*4] = w;   // 4 consecutive tokens
            }
        }
        __syncthreads();

        const int t7 = tid & 127, hloc = tid >> 7;
        const int bh = (row0 >> 11) * 12 + ((col0 - 1536) >> 6) + hloc;
        const int kg0 = (row0 & 2047) >> 5;
        u16* dst = Vt + (size_t)bh * 131072 + (size_t)kg0 * 2048;
        #pragma unroll
        for (int i = 0; i < 8; i++) {
            const int idx = t7 + 128*i;                  // 0..1023 per head
            const int L = idx & 63, f = (idx >> 6) & 3, lkg = idx >> 8;
            const int lr = L & 31, hl = L >> 5;
            const u16* src = &T[(hloc*64 + (f>>1)*32 + lr)*132 + lkg*32 + (f&1)*16 + hl*4];
            union { u16x8 v; u16x4 h[2]; } rr;
            rr.h[0] = *(const u16x4*)src;        // keys +0..3
            rr.h[1] = *(const u16x4*)(src + 8);  // keys +8..11
            *(u16x8*)&dst[lkg*2048 + f*512 + L*8] = rr.v;
        }
    }
}

// Proj: 64x64 tiles (768 blocks). BK=64 + XOR swizzle. fp32 out + bias.
__global__ __launch_bounds__(256, 4) void gemm_proj(
    const u16* __restrict__ A, const u16* __restrict__ W,
    const float* __restrict__ bias, float* __restrict__ F0)
{
    __shared__ alignas(16) u16 As[64 * 64];
    __shared__ alignas(16) u16 Bs[64 * 64];
    const int tid  = threadIdx.x;
    const int wid  = tid >> 6, lane = tid & 63;
    const int quad = lane >> 4, lc = lane & 15;
    const int row0 = blockIdx.x * 64, col0 = blockIdx.y * 64;
    const int wm   = (wid >> 1) * 32, wn = (wid & 1) * 32;

    const int srA = wid * 8 + (lane >> 3);
    const int scA = ((lane & 7) ^ ((lane >> 3) & 7)) * 8;
    const int rc0 = ((0*4 + quad) ^ (lc & 7)) * 8;
    const int rc1 = ((1*4 + quad) ^ (lc & 7)) * 8;

    f32x4 acc[2][2] = {};

    for (int k0 = 0; k0 < 768; k0 += 64) {
        __syncthreads();
        #pragma unroll
        for (int c = 0; c < 2; c++) {
            load16_async(&A[(row0 + c*32 + srA) * 768 + k0 + scA], &As[(c*32 + wid*8) * 64]);
            load16_async(&W[(col0 + c*32 + srA) * 768 + k0 + scA], &Bs[(c*32 + wid*8) * 64]);
        }
        __syncthreads();

        #pragma unroll
        for (int s = 0; s < 2; s++) {
            const int rc = s ? rc1 : rc0;
            bf16x8 a[2], b[2];
            #pragma unroll
            for (int i = 0; i < 2; i++)
                a[i] = __builtin_bit_cast(bf16x8, *(const u16x8*)&As[(wm + i*16 + lc)*64 + rc]);
            #pragma unroll
            for (int j = 0; j < 2; j++)
                b[j] = __builtin_bit_cast(bf16x8, *(const u16x8*)&Bs[(wn + j*16 + lc)*64 + rc]);
            #pragma unroll
            for (int i = 0; i < 2; i++)
                #pragma unroll
                for (int j = 0; j < 2; j++)
                    acc[i][j] = __builtin_amdgcn_mfma_f32_16x16x32_bf16(a[i], b[j], acc[i][j], 0, 0, 0);
        }
    }

    #pragma unroll
    for (int i = 0; i < 2; i++)
        #pragma unroll
        for (int j = 0; j < 2; j++) {
            const int gc = col0 + wn + j*16 + lc;
            const float bv = bias[gc];
            #pragma unroll
            for (int r = 0; r < 4; r++) {
                const int gr = row0 + wm + i*16 + quad*4 + r;
                F0[gr * 768 + gc] = acc[i][j][r] + bv;
            }
        }
}

// Flash attention, R6: zero-LDS main loop (R5) + SERIAL q-halves to kill the
// register spill (R5 peaked ~180 regs > 168 cap -> 17MB scratch writes).
// One S accumulator (16) reused by both halves; P packed to 8 regs right
// after softmax; K prefetch after its last use. Peak ~154 regs -> no spill.
__global__ __launch_bounds__(256, 3) void attn_k(
    const u16* __restrict__ Q, const u16* __restrict__ Kt,
    const u16* __restrict__ Vt, u16* __restrict__ O)
{
    __shared__ alignas(16) char lds[34304];
    float* Obuf = (float*)lds;             // [4][64][33] f32 = 33792 B
    float* Lbuf = (float*)(lds + 33792);   // [4][32] f32

    const int tid  = threadIdx.x;
    const int wid  = tid >> 6, lane = tid & 63;
    const int hl   = lane >> 5;            // k-slot half selector
    const int lr   = lane & 31;
    const int li = blockIdx.x;
    const int bh = li >> 5, qt = li & 31;
    const int b = bh / 12, h = bh - b * 12;
    const int q0 = qt * 64;

    const u16* Qp = Q + ((size_t)b * 2048) * 768 + h * 64;
    u16*       Op = O + ((size_t)b * 2048) * 768 + h * 64;
    const u16* Kb = Kt + (size_t)bh * 131072;
    const u16* Vb = Vt + (size_t)bh * 131072;
    const int lo8 = lane * 8;

    // Q fragments (B-operand), two q-halves; scale = 1/8 * log2(e)
    const float qs = 0.125f * 1.4426950408889634f;
    bf16x8 qf[2][4];
    #pragma unroll
    for (int qh = 0; qh < 2; qh++)
        #pragma unroll
        for (int c = 0; c < 4; c++) {
            u16x8 t = *(const u16x8*)&Qp[(q0 + qh*32 + lr) * 768 + c*16 + hl*8];
            bf16x8 sc;
            #pragma unroll
            for (int e = 0; e < 8; e++) {
                union { uint32_t u; float f; } z; z.u = ((uint32_t)t[e]) << 16;
                sc[e] = (__bf16)(z.f * qs);
            }
            qf[qh][c] = sc;
        }

    float l0 = 0.f, l1 = 0.f;
    f32x16 o00 = {}, o01 = {}, o10 = {}, o11 = {};  // [qh][d-half], q = lr

    // prefetch K fragments for key-group wid (iter 0)
    bf16x8 kreg[4];
    #pragma unroll
    for (int c = 0; c < 4; c++)
        kreg[c] = __builtin_bit_cast(bf16x8, *(const u16x8*)&Kb[wid*2048 + c*512 + lo8]);

    for (int kt = 0; kt < 16; kt++) {
        const int kg = kt*4 + wid;
        const u16* vt = &Vb[(size_t)kg * 2048 + lo8];
        // V fragment loads issued early; consumed at PV h0
        u16x8 va0r = *(const u16x8*)&vt[0];
        u16x8 va1r = *(const u16x8*)&vt[512];
        u16x8 vb0r = *(const u16x8*)&vt[1024];
        u16x8 vb1r = *(const u16x8*)&vt[1536];

        // ---- q-half 0: QK^T -> softmax -> pack -> PV ----
        f32x16 s = {};
        __builtin_amdgcn_s_setprio(1);
        #pragma unroll
        for (int c = 0; c < 4; c++)
            s = __builtin_amdgcn_mfma_f32_32x32x16_bf16(kreg[c], qf[0][c], s, 0, 0, 0);
        __builtin_amdgcn_s_setprio(0);

        #pragma unroll
        for (int r = 0; r < 16; r++) {
            float p = ex2(s[r]);
            s[r] = p;
            l0 += p;
        }
        union { bf16x8 v; uint32_t w[4]; } pA, pB;
        #pragma unroll
        for (int e2 = 0; e2 < 4; e2++) {
            pA.w[e2] = pk2(s[2*e2],     s[2*e2 + 1]);
            pB.w[e2] = pk2(s[8 + 2*e2], s[8 + 2*e2 + 1]);
        }
        {
            bf16x8 va0 = __builtin_bit_cast(bf16x8, va0r);
            bf16x8 va1 = __builtin_bit_cast(bf16x8, va1r);
            bf16x8 vb0 = __builtin_bit_cast(bf16x8, vb0r);
            bf16x8 vb1 = __builtin_bit_cast(bf16x8, vb1r);
            __builtin_amdgcn_s_setprio(1);
            o00 = __builtin_amdgcn_mfma_f32_32x32x16_bf16(va0, pA.v, o00, 0, 0, 0);
            o00 = __builtin_amdgcn_mfma_f32_32x32x16_bf16(va1, pB.v, o00, 0, 0, 0);
            o01 = __builtin_amdgcn_mfma_f32_32x32x16_bf16(vb0, pA.v, o01, 0, 0, 0);
            o01 = __builtin_amdgcn_mfma_f32_32x32x16_bf16(vb1, pB.v, o01, 0, 0, 0);
            __builtin_amdgcn_s_setprio(0);
        }

        // ---- q-half 1: QK^T (same S regs) -> K prefetch -> softmax -> PV ----
        f32x16 t = {};
        __builtin_amdgcn_s_setprio(1);
        #pragma unroll
        for (int c = 0; c < 4; c++)
            t = __builtin_amdgcn_mfma_f32_32x32x16_bf16(kreg[c], qf[1][c], t, 0, 0, 0);
        __builtin_amdgcn_s_setprio(0);

        if (kt < 15) {
            #pragma unroll
            for (int c = 0; c < 4; c++)
                kreg[c] = __builtin_bit_cast(bf16x8, *(const u16x8*)&Kb[(size_t)(kg + 4)*2048 + c*512 + lo8]);
        }

        #pragma unroll
        for (int r = 0; r < 16; r++) {
            float p = ex2(t[r]);
            t[r] = p;
            l1 += p;
        }
        union { bf16x8 v; uint32_t w[4]; } pC, pD;
        #pragma unroll
        for (int e2 = 0; e2 < 4; e2++) {
            pC.w[e2] = pk2(t[2*e2],     t[2*e2 + 1]);
            pD.w[e2] = pk2(t[8 + 2*e2], t[8 + 2*e2 + 1]);
        }
        {
            bf16x8 va0 = __builtin_bit_cast(bf16x8, va0r);
            bf16x8 va1 = __builtin_bit_cast(bf16x8, va1r);
            bf16x8 vb0 = __builtin_bit_cast(bf16x8, vb0r);
            bf16x8 vb1 = __builtin_bit_cast(bf16x8, vb1r);
            __builtin_amdgcn_s_setprio(1);
            o10 = __builtin_amdgcn_mfma_f32_32x32x16_bf16(va0, pC.v, o10, 0, 0, 0);
            o10 = __builtin_amdgcn_mfma_f32_32x32x16_bf16(va1, pD.v, o10, 0, 0, 0);
            o11 = __builtin_amdgcn_mfma_f32_32x32x16_bf16(vb0, pC.v, o11, 0, 0, 0);
            o11 = __builtin_amdgcn_mfma_f32_32x32x16_bf16(vb1, pD.v, o11, 0, 0, 0);
            __builtin_amdgcn_s_setprio(0);
        }
    }

    // ---- epilogue: cross-wave reduction over key slices, per q-half ----
    l0 += __shfl_xor(l0, 32);    // combine hl halves (same q, disjoint keys)
    l1 += __shfl_xor(l1, 32);

    const int q  = tid & 31;     // epilogue q (within half)
    const int dblk = tid >> 5;   // epilogue d block (0..7), 8 d each

    // q-half 0
    if (lane < 32) Lbuf[wid*32 + lr] = l0;
    #pragma unroll
    for (int r = 0; r < 16; r++) {
        const int dr = (r & 3) + 8*(r >> 2) + 4*hl;
        Obuf[(wid*64 + dr)*33 + lr]      = o00[r];
        Obuf[(wid*64 + 32 + dr)*33 + lr] = o01[r];
    }
    __syncthreads();
    {
        const float linv = 1.0f / (Lbuf[q] + Lbuf[32 + q] + Lbuf[64 + q] + Lbuf[96 + q]);
        u16x8 ov;
        #pragma unroll
        for (int j = 0; j < 8; j++) {
            const int d = dblk*8 + j;
            const float sum = Obuf[(0*64 + d)*33 + q] + Obuf[(1*64 + d)*33 + q] +
                              Obuf[(2*64 + d)*33 + q] + Obuf[(3*64 + d)*33 + q];
            ov[j] = f2b(sum * linv);
        }
        *(u16x8*)&Op[(size_t)(q0 + q) * 768 + dblk*8] = ov;
    }
    __syncthreads();

    // q-half 1
    if (lane < 32) Lbuf[wid*32 + lr] = l1;
    #pragma unroll
    for (int r = 0; r < 16; r++) {
        const int dr = (r & 3) + 8*(r >> 2) + 4*hl;
        Obuf[(wid*64 + dr)*33 + lr]      = o10[r];
        Obuf[(wid*64 + 32 + dr)*33 + lr] = o11[r];
    }
    __syncthreads();
    {
        const float linv = 1.0f / (Lbuf[q] + Lbuf[32 + q] + Lbuf[64 + q] + Lbuf[96 + q]);
        u16x8 ov;
        #pragma unroll
        for (int j = 0; j < 8; j++) {
            const int d = dblk*8 + j;
            const float sum = Obuf[(0*64 + d)*33 + q] + Obuf[(1*64 + d)*33 + q] +
                              Obuf[(2*64 + d)*33 + q] + Obuf[(3*64 + d)*33 + q];
            ov[j] = f2b(sum * linv);
        }
        *(u16x8*)&Op[(size_t)(q0 + 32 + q) * 768 + dblk*8] = ov;
    }
}

extern "C" void kernel_launch(void* const* d_in, const int* in_sizes, int n_in,
                              void* d_out, int out_size, void* d_ws, size_t ws_size,
                              hipStream_t stream)
{
    const float* x    = (const float*)d_in[0];   // [2,2048,768] fp32
    const float* wqkv = (const float*)d_in[1];   // [2304,768]   fp32
    const float* bqkv = (const float*)d_in[2];   // [2304]       fp32
    const float* wp   = (const float*)d_in[3];   // [768,768]    fp32
    const float* bp   = (const float*)d_in[4];   // [768]        fp32
    float* out = (float*)d_out;                  // [2,2048,768] fp32
    char* ws = (char*)d_ws;

    // ws: Qw 6.29M | Vt 6.29M | wqkvb 3.54M | wpb 1.18M = 17.3M (proven available)
    // d_out (12.58M fp32): front = Kt (fragment-major bf16, 6.29M), back = xb
    // bf16 6.29M; both dead before gemm_proj overwrites d_out (stream-ordered).
    u16* Qw    = (u16*)(ws);
    u16* Vt    = (u16*)(ws + 6291456);
    u16* wqkvb = (u16*)(ws + 12582912);
    u16* wpb   = (u16*)(ws + 16121856);
    u16* Kt    = (u16*)d_out;
    u16* xb    = (u16*)((char*)d_out + 6291456);

    conv_k<<<512, 256, 0, stream>>>(x, xb, 3145728/4, wqkv, wqkvb, 1769472/4, wp, wpb, 589824/4);
    gemm_qkv<<<dim3(32, 18), 256, 0, stream>>>(xb, wqkvb, bqkv, Qw, Kt, Vt);
    attn_k<<<768, 256, 0, stream>>>(Qw, Kt, Vt, Qw);
    gemm_proj<<<dim3(64, 12), 256, 0, stream>>>(Qw, wpb, bp, out);
}